// Round 3
// baseline (70.442 us; speedup 1.0000x reference)
//
#include <hip/hip_runtime.h>
#include <math.h>

#define DIM 64
#define NE 4
#define B_SZ 4
#define NQ 4096
#define NK 4096
#define BQ 16     // q-rows per writer block
#define KT 1024   // k-cols per writer block

typedef float fvec4 __attribute__((ext_vector_type(4)));

// ---------------------------------------------------------------------------
// Kernel 1: per-row features. One 64-lane wave per row.
//   qf[e=0] = amp * exp(-0.5*surf(q)^2)        kf[e=0] = exp(-0.5*surf(k)^2)
//   qf[e>0] = amp * exp(-0.5*||q-p_e||^2)      kf[e>0] = w_e * exp(-0.5*||k-p_e||^2)
// Layout: feat-major  f[b][e][row]  so the writer's loads are coalesced.
// ---------------------------------------------------------------------------
__global__ __launch_bounds__(256) void feat_kernel(
    const float* __restrict__ queries,
    const float* __restrict__ keys,
    const float* __restrict__ center,
    const float* __restrict__ outer_radius,
    const float* __restrict__ hole_radius,
    const float* __restrict__ entry_points,
    const float* __restrict__ entry_strengths,
    const float* __restrict__ amplitude,
    float* __restrict__ qf,   // [B][5][NQ]
    float* __restrict__ kf)   // [B][5][NK]
{
    const int wave = (blockIdx.x * blockDim.x + threadIdx.x) >> 6;
    const int lane = threadIdx.x & 63;
    const int nqrows = B_SZ * NQ;
    const int total  = nqrows + B_SZ * NK;
    if (wave >= total) return;

    const bool is_q = wave < nqrows;
    const int  row  = is_q ? wave : (wave - nqrows);
    const float* src = is_q ? (queries + (size_t)row * DIM)
                            : (keys    + (size_t)row * DIM);

    const float x = src[lane];

    float d0 = x - center[lane];
    float d1 = x - entry_points[0 * DIM + lane];
    float d2 = x - entry_points[1 * DIM + lane];
    float d3 = x - entry_points[2 * DIM + lane];
    float d4 = x - entry_points[3 * DIM + lane];
    float a0 = d0 * d0;
    float a1 = d1 * d1;
    float a2 = d2 * d2;
    float a3 = d3 * d3;
    float a4 = d4 * d4;

    #pragma unroll
    for (int off = 32; off >= 1; off >>= 1) {
        a0 += __shfl_xor(a0, off, 64);
        a1 += __shfl_xor(a1, off, 64);
        a2 += __shfl_xor(a2, off, 64);
        a3 += __shfl_xor(a3, off, 64);
        a4 += __shfl_xor(a4, off, 64);
    }

    if (lane == 0) {
        const float outer_r    = fabsf(outer_radius[0]) + 1e-8f;
        const float hole_r     = fabsf(hole_radius[0]);
        const float hole_ratio = hole_r / outer_r;
        const float amp        = amplitude[0];

        const float dist  = sqrtf(a0);
        const float major = fabsf(dist - outer_r);
        const float torus = fabsf(sqrtf(major * major + hole_r * hole_r) - hole_r);
        const float surf  = (hole_ratio < 0.1f) ? major : torus;

        const float f0 = expf(-0.5f * surf * surf);
        const float f1 = expf(-0.5f * a1);
        const float f2 = expf(-0.5f * a2);
        const float f3 = expf(-0.5f * a3);
        const float f4 = expf(-0.5f * a4);

        const int b = row / (is_q ? NQ : NK);
        const int r = row - b * (is_q ? NQ : NK);

        if (is_q) {
            float* dst = qf + ((size_t)b * 5) * NQ + r;
            dst[0 * NQ] = amp * f0;
            dst[1 * NQ] = amp * f1;
            dst[2 * NQ] = amp * f2;
            dst[3 * NQ] = amp * f3;
            dst[4 * NQ] = amp * f4;
        } else {
            float w[NE];
            #pragma unroll
            for (int e = 0; e < NE; ++e) {
                float s = 1.0f / (1.0f + expf(-entry_strengths[e]));
                w[e] = (s > 0.1f) ? s : 0.0f;
            }
            float* dst = kf + ((size_t)b * 5) * NK + r;
            dst[0 * NK] = f0;
            dst[1 * NK] = w[0] * f1;
            dst[2 * NK] = w[1] * f2;
            dst[3 * NK] = w[2] * f3;
            dst[4 * NK] = w[3] * f4;
        }
    }
}

// ---------------------------------------------------------------------------
// Kernel 2: streaming writer. out[b,q,k] = dot5(qf[b,:,q], kf[b,:,k]).
// Block = 256 threads handles BQ=16 rows x KT=1024 cols.
// Non-temporal fvec4 stores: output is write-once, don't churn L2.
// ---------------------------------------------------------------------------
__global__ __launch_bounds__(256) void write_kernel(
    const float* __restrict__ qf,
    const float* __restrict__ kf,
    float* __restrict__ out)
{
    const int b  = blockIdx.z;
    const int q0 = blockIdx.y * BQ;
    const int k0 = blockIdx.x * KT + threadIdx.x * 4;

    const float* qfb = qf + ((size_t)b * 5) * NQ + q0;
    const float* kfb = kf + ((size_t)b * 5) * NK + k0;

    fvec4 kc[5];
    #pragma unroll
    for (int e = 0; e < 5; ++e)
        kc[e] = *reinterpret_cast<const fvec4*>(kfb + (size_t)e * NK);

    float qv[5][BQ];
    #pragma unroll
    for (int e = 0; e < 5; ++e)
        #pragma unroll
        for (int r = 0; r < BQ; ++r)
            qv[e][r] = qfb[(size_t)e * NQ + r];

    float* orow = out + ((size_t)(b * NQ + q0)) * NK + k0;

    #pragma unroll
    for (int r = 0; r < BQ; ++r) {
        fvec4 v = qv[0][r] * kc[0] + qv[1][r] * kc[1] + qv[2][r] * kc[2]
                + qv[3][r] * kc[3] + qv[4][r] * kc[4];
        __builtin_nontemporal_store(v, reinterpret_cast<fvec4*>(orow + (size_t)r * NK));
    }
}

extern "C" void kernel_launch(void* const* d_in, const int* in_sizes, int n_in,
                              void* d_out, int out_size, void* d_ws, size_t ws_size,
                              hipStream_t stream) {
    const float* queries         = (const float*)d_in[0];
    const float* keys            = (const float*)d_in[1];
    const float* center          = (const float*)d_in[2];
    const float* outer_radius    = (const float*)d_in[3];
    const float* hole_radius     = (const float*)d_in[4];
    const float* entry_points    = (const float*)d_in[5];
    const float* entry_strengths = (const float*)d_in[6];
    const float* amplitude       = (const float*)d_in[7];

    float* qf = (float*)d_ws;                              // B*5*NQ floats
    float* kf = qf + (size_t)B_SZ * 5 * NQ;                // B*5*NK floats
    float* out = (float*)d_out;

    // Kernel 1: 32768 rows, 4 waves/block -> 8192 blocks
    {
        const int total_rows = B_SZ * NQ + B_SZ * NK;
        const int waves_per_block = 4;
        const int blocks = (total_rows + waves_per_block - 1) / waves_per_block;
        feat_kernel<<<blocks, 256, 0, stream>>>(
            queries, keys, center, outer_radius, hole_radius,
            entry_points, entry_strengths, amplitude, qf, kf);
    }

    // Kernel 2: (NK/KT, NQ/BQ, B) = (4, 256, 4) blocks of 256
    {
        dim3 grid(NK / KT, NQ / BQ, B_SZ);
        write_kernel<<<grid, 256, 0, stream>>>(qf, kf, out);
    }
}

// Round 4
// 60.495 us; speedup vs baseline: 1.1644x; 1.1644x over previous
//
#include <hip/hip_runtime.h>
#include <math.h>

#define DIM 64
#define NE 4
#define B_SZ 4
#define NQ 4096
#define NK 4096
#define BQ 8      // q-rows per writer block

typedef float fvec4 __attribute__((ext_vector_type(4)));

// ---------------------------------------------------------------------------
// Kernel 1: per-row features. One 64-lane wave per row.
//   qf[e=0] = amp * exp(-0.5*surf(q)^2)        kf[e=0] = exp(-0.5*surf(k)^2)
//   qf[e>0] = amp * exp(-0.5*||q-p_e||^2)      kf[e>0] = w_e * exp(-0.5*||k-p_e||^2)
// Layout: feat-major  f[b][e][row]  so the writer's loads are coalesced.
// ---------------------------------------------------------------------------
__global__ __launch_bounds__(256) void feat_kernel(
    const float* __restrict__ queries,
    const float* __restrict__ keys,
    const float* __restrict__ center,
    const float* __restrict__ outer_radius,
    const float* __restrict__ hole_radius,
    const float* __restrict__ entry_points,
    const float* __restrict__ entry_strengths,
    const float* __restrict__ amplitude,
    float* __restrict__ qf,   // [B][5][NQ]
    float* __restrict__ kf)   // [B][5][NK]
{
    const int wave = (blockIdx.x * blockDim.x + threadIdx.x) >> 6;
    const int lane = threadIdx.x & 63;
    const int nqrows = B_SZ * NQ;
    const int total  = nqrows + B_SZ * NK;
    if (wave >= total) return;

    const bool is_q = wave < nqrows;
    const int  row  = is_q ? wave : (wave - nqrows);
    const float* src = is_q ? (queries + (size_t)row * DIM)
                            : (keys    + (size_t)row * DIM);

    const float x = src[lane];

    float d0 = x - center[lane];
    float d1 = x - entry_points[0 * DIM + lane];
    float d2 = x - entry_points[1 * DIM + lane];
    float d3 = x - entry_points[2 * DIM + lane];
    float d4 = x - entry_points[3 * DIM + lane];
    float a0 = d0 * d0;
    float a1 = d1 * d1;
    float a2 = d2 * d2;
    float a3 = d3 * d3;
    float a4 = d4 * d4;

    #pragma unroll
    for (int off = 32; off >= 1; off >>= 1) {
        a0 += __shfl_xor(a0, off, 64);
        a1 += __shfl_xor(a1, off, 64);
        a2 += __shfl_xor(a2, off, 64);
        a3 += __shfl_xor(a3, off, 64);
        a4 += __shfl_xor(a4, off, 64);
    }

    if (lane == 0) {
        const float outer_r    = fabsf(outer_radius[0]) + 1e-8f;
        const float hole_r     = fabsf(hole_radius[0]);
        const float hole_ratio = hole_r / outer_r;
        const float amp        = amplitude[0];

        const float dist  = sqrtf(a0);
        const float major = fabsf(dist - outer_r);
        const float torus = fabsf(sqrtf(major * major + hole_r * hole_r) - hole_r);
        const float surf  = (hole_ratio < 0.1f) ? major : torus;

        const float f0 = expf(-0.5f * surf * surf);
        const float f1 = expf(-0.5f * a1);
        const float f2 = expf(-0.5f * a2);
        const float f3 = expf(-0.5f * a3);
        const float f4 = expf(-0.5f * a4);

        const int b = row / (is_q ? NQ : NK);
        const int r = row - b * (is_q ? NQ : NK);

        if (is_q) {
            float* dst = qf + ((size_t)b * 5) * NQ + r;
            dst[0 * NQ] = amp * f0;
            dst[1 * NQ] = amp * f1;
            dst[2 * NQ] = amp * f2;
            dst[3 * NQ] = amp * f3;
            dst[4 * NQ] = amp * f4;
        } else {
            float w[NE];
            #pragma unroll
            for (int e = 0; e < NE; ++e) {
                float s = 1.0f / (1.0f + expf(-entry_strengths[e]));
                w[e] = (s > 0.1f) ? s : 0.0f;
            }
            float* dst = kf + ((size_t)b * 5) * NK + r;
            dst[0 * NK] = f0;
            dst[1 * NK] = w[0] * f1;
            dst[2 * NK] = w[1] * f2;
            dst[3 * NK] = w[2] * f3;
            dst[4 * NK] = w[3] * f4;
        }
    }
}

// ---------------------------------------------------------------------------
// Kernel 2: streaming writer. out[b,q,k] = dot5(qf[b,:,q], kf[b,:,k]).
// Block = 256 threads owns BQ=8 rows x ALL 4096 cols (4 column-groups).
// Per thread: 10 uniform fvec4 q-loads + 20 fvec4 k-loads vs 32 fvec4 stores
// -> loads/store ~0.94 (was 5.6): keep the VMEM pipe issuing stores.
// ---------------------------------------------------------------------------
__global__ __launch_bounds__(256) void write_kernel(
    const float* __restrict__ qf,
    const float* __restrict__ kf,
    float* __restrict__ out)
{
    const int b   = blockIdx.y;
    const int q0  = blockIdx.x * BQ;
    const int tid = threadIdx.x;

    const float* qfb = qf + ((size_t)b * 5) * NQ + q0;
    const float* kfb = kf + ((size_t)b * 5) * NK;

    // q-features for 8 rows, vector-loaded (block-uniform -> broadcast)
    float qv[5][BQ];
    #pragma unroll
    for (int e = 0; e < 5; ++e) {
        fvec4 lo = *reinterpret_cast<const fvec4*>(qfb + (size_t)e * NQ);
        fvec4 hi = *reinterpret_cast<const fvec4*>(qfb + (size_t)e * NQ + 4);
        qv[e][0] = lo.x; qv[e][1] = lo.y; qv[e][2] = lo.z; qv[e][3] = lo.w;
        qv[e][4] = hi.x; qv[e][5] = hi.y; qv[e][6] = hi.z; qv[e][7] = hi.w;
    }

    float* ob = out + ((size_t)(b * NQ + q0)) * NK;

    #pragma unroll
    for (int cg = 0; cg < NK / 1024; ++cg) {
        const int k0 = cg * 1024 + tid * 4;
        fvec4 kc[5];
        #pragma unroll
        for (int e = 0; e < 5; ++e)
            kc[e] = *reinterpret_cast<const fvec4*>(kfb + (size_t)e * NK + k0);

        #pragma unroll
        for (int r = 0; r < BQ; ++r) {
            fvec4 v = qv[0][r] * kc[0] + qv[1][r] * kc[1] + qv[2][r] * kc[2]
                    + qv[3][r] * kc[3] + qv[4][r] * kc[4];
            *reinterpret_cast<fvec4*>(ob + (size_t)r * NK + k0) = v;
        }
    }
}

extern "C" void kernel_launch(void* const* d_in, const int* in_sizes, int n_in,
                              void* d_out, int out_size, void* d_ws, size_t ws_size,
                              hipStream_t stream) {
    const float* queries         = (const float*)d_in[0];
    const float* keys            = (const float*)d_in[1];
    const float* center          = (const float*)d_in[2];
    const float* outer_radius    = (const float*)d_in[3];
    const float* hole_radius     = (const float*)d_in[4];
    const float* entry_points    = (const float*)d_in[5];
    const float* entry_strengths = (const float*)d_in[6];
    const float* amplitude       = (const float*)d_in[7];

    float* qf = (float*)d_ws;                              // B*5*NQ floats
    float* kf = qf + (size_t)B_SZ * 5 * NQ;                // B*5*NK floats
    float* out = (float*)d_out;

    // Kernel 1: 32768 rows, 4 waves/block -> 8192 blocks
    {
        const int total_rows = B_SZ * NQ + B_SZ * NK;
        const int waves_per_block = 4;
        const int blocks = (total_rows + waves_per_block - 1) / waves_per_block;
        feat_kernel<<<blocks, 256, 0, stream>>>(
            queries, keys, center, outer_radius, hole_radius,
            entry_points, entry_strengths, amplitude, qf, kf);
    }

    // Kernel 2: (NQ/BQ, B) = (512, 4) blocks of 256
    {
        dim3 grid(NQ / BQ, B_SZ);
        write_kernel<<<grid, 256, 0, stream>>>(qf, kf, out);
    }
}

// Round 5
// 54.068 us; speedup vs baseline: 1.3028x; 1.1189x over previous
//
#include <hip/hip_runtime.h>
#include <math.h>

#define DIM 64
#define NE 4
#define B_SZ 4
#define NQ 4096
#define NK 4096
#define BQ 8      // q-rows per writer block

typedef float fvec4 __attribute__((ext_vector_type(4)));

// ---------------------------------------------------------------------------
// Kernel 1: per-row features, THREAD-per-row (no shuffles, no lane-0 tail).
// Each thread reads its 64-dim row as 16 fvec4, accumulates 5 squared
// distances, computes 5 expf in-lane, stores coalesced (lane-consec n).
//   qf[e=0] = amp * exp(-0.5*surf(q)^2)        kf[e=0] = exp(-0.5*surf(k)^2)
//   qf[e>0] = amp * exp(-0.5*||q-p_e||^2)      kf[e>0] = w_e * exp(-0.5*||k-p_e||^2)
// ---------------------------------------------------------------------------
__global__ __launch_bounds__(256) void feat_kernel(
    const float* __restrict__ queries,
    const float* __restrict__ keys,
    const float* __restrict__ center,
    const float* __restrict__ outer_radius,
    const float* __restrict__ hole_radius,
    const float* __restrict__ entry_points,
    const float* __restrict__ entry_strengths,
    const float* __restrict__ amplitude,
    float* __restrict__ qf,   // [B][5][NQ]
    float* __restrict__ kf)   // [B][5][NK]
{
    const int row = blockIdx.x * blockDim.x + threadIdx.x;   // 0..32767
    const int nqrows = B_SZ * NQ;
    const bool is_q = row < nqrows;
    const int  r    = is_q ? row : row - nqrows;             // 0..16383
    const float* src = (is_q ? queries : keys) + (size_t)r * DIM;

    float a0 = 0.f, a1 = 0.f, a2 = 0.f, a3 = 0.f, a4 = 0.f;

    #pragma unroll
    for (int j = 0; j < DIM / 4; ++j) {
        const fvec4 v  = *reinterpret_cast<const fvec4*>(src + j * 4);
        const fvec4 c  = *reinterpret_cast<const fvec4*>(center + j * 4);
        const fvec4 p0 = *reinterpret_cast<const fvec4*>(entry_points + 0 * DIM + j * 4);
        const fvec4 p1 = *reinterpret_cast<const fvec4*>(entry_points + 1 * DIM + j * 4);
        const fvec4 p2 = *reinterpret_cast<const fvec4*>(entry_points + 2 * DIM + j * 4);
        const fvec4 p3 = *reinterpret_cast<const fvec4*>(entry_points + 3 * DIM + j * 4);
        #pragma unroll
        for (int cc = 0; cc < 4; ++cc) {
            const float x  = v[cc];
            const float d0 = x - c[cc];
            const float d1 = x - p0[cc];
            const float d2 = x - p1[cc];
            const float d3 = x - p2[cc];
            const float d4 = x - p3[cc];
            a0 += d0 * d0;
            a1 += d1 * d1;
            a2 += d2 * d2;
            a3 += d3 * d3;
            a4 += d4 * d4;
        }
    }

    const float outer_r    = fabsf(outer_radius[0]) + 1e-8f;
    const float hole_r     = fabsf(hole_radius[0]);
    const float hole_ratio = hole_r / outer_r;
    const float amp        = amplitude[0];

    const float dist  = sqrtf(a0);
    const float major = fabsf(dist - outer_r);
    const float torus = fabsf(sqrtf(major * major + hole_r * hole_r) - hole_r);
    const float surf  = (hole_ratio < 0.1f) ? major : torus;

    const float f0 = expf(-0.5f * surf * surf);
    const float f1 = expf(-0.5f * a1);
    const float f2 = expf(-0.5f * a2);
    const float f3 = expf(-0.5f * a3);
    const float f4 = expf(-0.5f * a4);

    const int b = r >> 12;          // r / 4096
    const int n = r & (NQ - 1);     // r % 4096

    if (is_q) {
        float* dst = qf + ((size_t)b * 5) * NQ + n;
        dst[0 * NQ] = amp * f0;
        dst[1 * NQ] = amp * f1;
        dst[2 * NQ] = amp * f2;
        dst[3 * NQ] = amp * f3;
        dst[4 * NQ] = amp * f4;
    } else {
        float w[NE];
        #pragma unroll
        for (int e = 0; e < NE; ++e) {
            float s = 1.0f / (1.0f + expf(-entry_strengths[e]));
            w[e] = (s > 0.1f) ? s : 0.0f;
        }
        float* dst = kf + ((size_t)b * 5) * NK + n;
        dst[0 * NK] = f0;
        dst[1 * NK] = w[0] * f1;
        dst[2 * NK] = w[1] * f2;
        dst[3 * NK] = w[2] * f3;
        dst[4 * NK] = w[3] * f4;
    }
}

// ---------------------------------------------------------------------------
// Kernel 2: streaming writer. out[b,q,k] = dot5(qf[b,:,q], kf[b,:,k]).
// Block = 256 threads owns BQ=8 rows x ALL 4096 cols (4 column-groups).
// (unchanged from R4)
// ---------------------------------------------------------------------------
__global__ __launch_bounds__(256) void write_kernel(
    const float* __restrict__ qf,
    const float* __restrict__ kf,
    float* __restrict__ out)
{
    const int b   = blockIdx.y;
    const int q0  = blockIdx.x * BQ;
    const int tid = threadIdx.x;

    const float* qfb = qf + ((size_t)b * 5) * NQ + q0;
    const float* kfb = kf + ((size_t)b * 5) * NK;

    float qv[5][BQ];
    #pragma unroll
    for (int e = 0; e < 5; ++e) {
        fvec4 lo = *reinterpret_cast<const fvec4*>(qfb + (size_t)e * NQ);
        fvec4 hi = *reinterpret_cast<const fvec4*>(qfb + (size_t)e * NQ + 4);
        qv[e][0] = lo.x; qv[e][1] = lo.y; qv[e][2] = lo.z; qv[e][3] = lo.w;
        qv[e][4] = hi.x; qv[e][5] = hi.y; qv[e][6] = hi.z; qv[e][7] = hi.w;
    }

    float* ob = out + ((size_t)(b * NQ + q0)) * NK;

    #pragma unroll
    for (int cg = 0; cg < NK / 1024; ++cg) {
        const int k0 = cg * 1024 + tid * 4;
        fvec4 kc[5];
        #pragma unroll
        for (int e = 0; e < 5; ++e)
            kc[e] = *reinterpret_cast<const fvec4*>(kfb + (size_t)e * NK + k0);

        #pragma unroll
        for (int r = 0; r < BQ; ++r) {
            fvec4 v = qv[0][r] * kc[0] + qv[1][r] * kc[1] + qv[2][r] * kc[2]
                    + qv[3][r] * kc[3] + qv[4][r] * kc[4];
            *reinterpret_cast<fvec4*>(ob + (size_t)r * NK + k0) = v;
        }
    }
}

extern "C" void kernel_launch(void* const* d_in, const int* in_sizes, int n_in,
                              void* d_out, int out_size, void* d_ws, size_t ws_size,
                              hipStream_t stream) {
    const float* queries         = (const float*)d_in[0];
    const float* keys            = (const float*)d_in[1];
    const float* center          = (const float*)d_in[2];
    const float* outer_radius    = (const float*)d_in[3];
    const float* hole_radius     = (const float*)d_in[4];
    const float* entry_points    = (const float*)d_in[5];
    const float* entry_strengths = (const float*)d_in[6];
    const float* amplitude       = (const float*)d_in[7];

    float* qf = (float*)d_ws;                              // B*5*NQ floats
    float* kf = qf + (size_t)B_SZ * 5 * NQ;                // B*5*NK floats
    float* out = (float*)d_out;

    // Kernel 1: 32768 rows, 1 thread/row -> 128 blocks of 256
    {
        const int total_rows = B_SZ * NQ + B_SZ * NK;
        feat_kernel<<<total_rows / 256, 256, 0, stream>>>(
            queries, keys, center, outer_radius, hole_radius,
            entry_points, entry_strengths, amplitude, qf, kf);
    }

    // Kernel 2: (NQ/BQ, B) = (512, 4) blocks of 256
    {
        dim3 grid(NQ / BQ, B_SZ);
        write_kernel<<<grid, 256, 0, stream>>>(qf, kf, out);
    }
}